// Round 11
// baseline (182.293 us; speedup 1.0000x reference)
//
#include <hip/hip_runtime.h>

#define HID 20

// Scalar SiLU via native exp2/rcp. Same per-lane formula/op-order as all
// prior rounds -> bit-identical results (absmax 0.0).
__device__ __forceinline__ float si(float a) {
    float e = __builtin_amdgcn_exp2f(-1.442695040888963f * a);
    return a * __builtin_amdgcn_rcpf(1.0f + e);
}

// Zero-cost allocator fence: forces all 20 values to be simultaneously live
// in ARCH VGPRs ("v" class -- AGPRs are "a") at this point. R8 evidence: the
// 1-pt kernel's allocator collapsed to 24 arch VGPRs and churned h/g through
// AGPR moves (busy 59->98us, WRITE flat = no memory spill). This pin makes
// that schedule illegal while costing zero instructions.
#define PIN20(A)                                                              \
    asm volatile("" : "+v"(A[0]), "+v"(A[1]), "+v"(A[2]), "+v"(A[3]),         \
                      "+v"(A[4]), "+v"(A[5]), "+v"(A[6]), "+v"(A[7]),         \
                      "+v"(A[8]), "+v"(A[9]), "+v"(A[10]), "+v"(A[11]),       \
                      "+v"(A[12]), "+v"(A[13]), "+v"(A[14]), "+v"(A[15]),     \
                      "+v"(A[16]), "+v"(A[17]), "+v"(A[18]), "+v"(A[19]))

// 20->20 layer on ONE point, j-blocked by 4 (4 independent acc chains).
// Weights via wave-uniform global pointers -> SGPR s_load bursts.
__device__ __forceinline__ void layer20_1(const float* __restrict__ W,
                                          const float* __restrict__ b,
                                          const float* __restrict__ h,
                                          float* __restrict__ o) {
    #pragma unroll
    for (int jb = 0; jb < HID; jb += 4) {
        float a0 = b[jb], a1 = b[jb + 1], a2 = b[jb + 2], a3 = b[jb + 3];
        #pragma unroll
        for (int i = 0; i < HID; ++i) {
            float x = h[i];
            a0 = __builtin_fmaf(x, W[(jb + 0) * HID + i], a0);
            a1 = __builtin_fmaf(x, W[(jb + 1) * HID + i], a1);
            a2 = __builtin_fmaf(x, W[(jb + 2) * HID + i], a2);
            a3 = __builtin_fmaf(x, W[(jb + 3) * HID + i], a3);
        }
        o[jb] = si(a0); o[jb + 1] = si(a1); o[jb + 2] = si(a2); o[jb + 3] = si(a3);
    }
}

// R11: 1-pt/thread (R8's 89%-duty structure) + PIN20 register fences (kill
// R8's AGPR churn) + R9's non-unrolled layer loop (I$ ~8KB) + (256,8)
// (64-VGPR budget; ~52 needed). Goal: R1's per-point stream at R8's duty.
// Tripwires: VGPR must be 48-64 (24 = pin failed); WRITE_SIZE ~4MB.
__global__ __launch_bounds__(256, 8) void SpringEquationNN_70102456205450_kernel(
    const float* __restrict__ t,
    const float* __restrict__ W0, const float* __restrict__ b0,
    const float* __restrict__ W1, const float* __restrict__ b1,
    const float* __restrict__ W2, const float* __restrict__ b2,
    const float* __restrict__ W3, const float* __restrict__ b3,
    const float* __restrict__ W4, const float* __restrict__ b4,
    const float* __restrict__ W5, const float* __restrict__ b5,
    const float* __restrict__ W6, const float* __restrict__ b6,
    const float* __restrict__ W7, const float* __restrict__ b7,
    float* __restrict__ out, int n)
{
    int idx = blockIdx.x * blockDim.x + threadIdx.x;   // point index
    if (idx >= n) return;

    float x = t[idx];   // 4B/lane, coalesced

    float h[HID], g[HID];

    // Layer 0: 1 -> 20
    #pragma unroll
    for (int j = 0; j < HID; ++j)
        h[j] = si(__builtin_fmaf(x, W0[j], b0[j]));
    PIN20(h);

    // Layers 1..6 as 3 iterations x (2 layers). MUST NOT unroll (I$: R9's
    // win came from fitting 32KB; loop keeps this ~8KB).
    #pragma unroll 1
    for (int it = 0; it < 3; ++it) {
        const float *Wa, *ba_, *Wb, *bb_;
        if (it == 0)      { Wa = W1; ba_ = b1; Wb = W2; bb_ = b2; }
        else if (it == 1) { Wa = W3; ba_ = b3; Wb = W4; bb_ = b4; }
        else              { Wa = W5; ba_ = b5; Wb = W6; bb_ = b6; }
        layer20_1(Wa, ba_, h, g);
        PIN20(g);
        layer20_1(Wb, bb_, g, h);
        PIN20(h);
    }

    // Layer 7: 20 -> 1, serial ascending-i chain (exact reference order).
    float acc = b7[0];
    #pragma unroll
    for (int i = 0; i < HID; ++i)
        acc = __builtin_fmaf(h[i], W7[i], acc);

    out[idx] = acc;   // 4B/lane, coalesced
}

extern "C" void kernel_launch(void* const* d_in, const int* in_sizes, int n_in,
                              void* d_out, int out_size, void* d_ws, size_t ws_size,
                              hipStream_t stream) {
    const float* t  = (const float*)d_in[0];
    const float* W0 = (const float*)d_in[1];
    const float* b0 = (const float*)d_in[2];
    const float* W1 = (const float*)d_in[3];
    const float* b1 = (const float*)d_in[4];
    const float* W2 = (const float*)d_in[5];
    const float* b2 = (const float*)d_in[6];
    const float* W3 = (const float*)d_in[7];
    const float* b3 = (const float*)d_in[8];
    const float* W4 = (const float*)d_in[9];
    const float* b4 = (const float*)d_in[10];
    const float* W5 = (const float*)d_in[11];
    const float* b5 = (const float*)d_in[12];
    const float* W6 = (const float*)d_in[13];
    const float* b6 = (const float*)d_in[14];
    const float* W7 = (const float*)d_in[15];
    const float* b7 = (const float*)d_in[16];
    float* out = (float*)d_out;

    int n = in_sizes[0];             // N points (1048576)
    int block = 256;
    int grid = (n + block - 1) / block;   // 4096
    SpringEquationNN_70102456205450_kernel<<<grid, block, 0, stream>>>(
        t, W0, b0, W1, b1, W2, b2, W3, b3, W4, b4, W5, b5, W6, b6, W7, b7,
        out, n);
}

// Round 12
// 163.222 us; speedup vs baseline: 1.1168x; 1.1168x over previous
//
#include <hip/hip_runtime.h>

#define HID 20

typedef float v2f __attribute__((ext_vector_type(2)));

// Native-instruction SiLU on a packed pair. exp/rcp are scalar trans ops
// (quarter-rate); surrounding muls pack. Formula bit-identical to all rounds.
__device__ __forceinline__ v2f silu2(v2f a) {
    v2f s = a * (-1.442695040888963f);
    float e0 = __builtin_amdgcn_exp2f(s.x);
    float e1 = __builtin_amdgcn_exp2f(s.y);
    v2f rc;
    rc.x = __builtin_amdgcn_rcpf(1.0f + e0);
    rc.y = __builtin_amdgcn_rcpf(1.0f + e1);
    return a * rc;
}

// 20->20 layer on a pair of points, j-blocked by 4 (R1's proven structure:
// 4 independent acc chains, SGPR weight bursts, ~59us busy-cycle stream).
template <int JB>
__device__ __forceinline__ void layer20(const float* __restrict__ W,
                                        const float* __restrict__ b,
                                        const v2f* __restrict__ h,
                                        v2f* __restrict__ hn) {
    static_assert(HID % JB == 0, "JB must divide HID");
    #pragma unroll
    for (int jb = 0; jb < HID; jb += JB) {
        v2f acc[JB];
        #pragma unroll
        for (int j = 0; j < JB; ++j) {
            float bj = b[jb + j];
            acc[j] = (v2f){bj, bj};
        }
        #pragma unroll
        for (int i = 0; i < HID; ++i) {
            v2f hi = h[i];
            #pragma unroll
            for (int j = 0; j < JB; ++j) {
                float w = W[(jb + j) * HID + i];
                acc[j] = __builtin_elementwise_fma(hi, (v2f){w, w}, acc[j]);
            }
        }
        #pragma unroll
        for (int j = 0; j < JB; ++j)
            hn[jb + j] = silu2(acc[j]);
    }
}

// R12 change vs R9 (80.3us best): __launch_bounds__(256, 6). Evidence table
// (occupancy tracks the DECLARED min in every clean run): min=3->37%,
// min=4->40%, min=8(1-pt, clean)->69%; min=8 on this 2-pt kernel paniced
// regalloc (budget 64 < fat live range -> 32reg+284MB scratch, R5). min=6
// gives budget ~85, nearly 2x the proven 44-reg schedule -> same stream,
// ~6 waves/SIMD provisioned to cover s_load waits + SiLU dep stalls.
// Tripwires: VGPR must stay ~44, WRITE_SIZE ~4MB (else panic recurred).
__global__ __launch_bounds__(256, 6) void SpringEquationNN_70102456205450_kernel(
    const float* __restrict__ t,
    const float* __restrict__ W0, const float* __restrict__ b0,
    const float* __restrict__ W1, const float* __restrict__ b1,
    const float* __restrict__ W2, const float* __restrict__ b2,
    const float* __restrict__ W3, const float* __restrict__ b3,
    const float* __restrict__ W4, const float* __restrict__ b4,
    const float* __restrict__ W5, const float* __restrict__ b5,
    const float* __restrict__ W6, const float* __restrict__ b6,
    const float* __restrict__ W7, const float* __restrict__ b7,
    float* __restrict__ out, int n)
{
    int idx = blockIdx.x * blockDim.x + threadIdx.x;   // pair index
    int p0 = 2 * idx;
    if (p0 >= n) return;

    // Coalesced 8B load of two consecutive points (N is even: 1048576).
    v2f x = *(const v2f*)(t + p0);

    v2f h[HID], hn[HID];

    // Layer 0: 1 -> 20 on both points
    #pragma unroll
    for (int j = 0; j < HID; ++j) {
        float w = W0[j], bb = b0[j];
        v2f a = __builtin_elementwise_fma(x, (v2f){w, w}, (v2f){bb, bb});
        h[j] = silu2(a);
    }

    // Layers 1..6 as 3 iterations x (2 layers). MUST NOT unroll (code size:
    // unrolled 2-pt is ~46KB > 32KB I$, pinned duty at 64-74% in R1-R7;
    // this loop form fits I$ and is the measured best, R9).
    #pragma unroll 1
    for (int it = 0; it < 3; ++it) {
        const float *Wa, *ba_, *Wb, *bb_;
        if (it == 0)      { Wa = W1; ba_ = b1; Wb = W2; bb_ = b2; }
        else if (it == 1) { Wa = W3; ba_ = b3; Wb = W4; bb_ = b4; }
        else              { Wa = W5; ba_ = b5; Wb = W6; bb_ = b6; }
        layer20<4>(Wa, ba_, h, hn);
        layer20<4>(Wb, bb_, hn, h);
    }

    // Layer 7: 20 -> 1 (no activation). Serial ascending-i chain preserves
    // the exact reference summation order.
    float b7v = b7[0];
    v2f acc = {b7v, b7v};
    #pragma unroll
    for (int i = 0; i < HID; ++i) {
        float w = W7[i];
        acc = __builtin_elementwise_fma(h[i], (v2f){w, w}, acc);
    }

    // Coalesced 8B store.
    *(v2f*)(out + p0) = acc;
}

extern "C" void kernel_launch(void* const* d_in, const int* in_sizes, int n_in,
                              void* d_out, int out_size, void* d_ws, size_t ws_size,
                              hipStream_t stream) {
    const float* t  = (const float*)d_in[0];
    const float* W0 = (const float*)d_in[1];
    const float* b0 = (const float*)d_in[2];
    const float* W1 = (const float*)d_in[3];
    const float* b1 = (const float*)d_in[4];
    const float* W2 = (const float*)d_in[5];
    const float* b2 = (const float*)d_in[6];
    const float* W3 = (const float*)d_in[7];
    const float* b3 = (const float*)d_in[8];
    const float* W4 = (const float*)d_in[9];
    const float* b4 = (const float*)d_in[10];
    const float* W5 = (const float*)d_in[11];
    const float* b5 = (const float*)d_in[12];
    const float* W6 = (const float*)d_in[13];
    const float* b6 = (const float*)d_in[14];
    const float* W7 = (const float*)d_in[15];
    const float* b7 = (const float*)d_in[16];
    float* out = (float*)d_out;

    int n = in_sizes[0];             // N points
    int pairs = (n + 1) / 2;         // threads (N=1048576 -> 524288)
    int block = 256;
    int grid = (pairs + block - 1) / block;
    SpringEquationNN_70102456205450_kernel<<<grid, block, 0, stream>>>(
        t, W0, b0, W1, b1, W2, b2, W3, b3, W4, b4, W5, b5, W6, b6, W7, b7,
        out, n);
}

// Round 13
// 160.509 us; speedup vs baseline: 1.1357x; 1.0169x over previous
//
#include <hip/hip_runtime.h>

#define HID 20

typedef float v2f __attribute__((ext_vector_type(2)));

// Native-instruction SiLU on a packed pair. exp/rcp are scalar trans ops
// (quarter-rate); surrounding muls pack. Formula bit-identical to all rounds.
__device__ __forceinline__ v2f silu2(v2f a) {
    v2f s = a * (-1.442695040888963f);
    float e0 = __builtin_amdgcn_exp2f(s.x);
    float e1 = __builtin_amdgcn_exp2f(s.y);
    v2f rc;
    rc.x = __builtin_amdgcn_rcpf(1.0f + e0);
    rc.y = __builtin_amdgcn_rcpf(1.0f + e1);
    return a * rc;
}

// 20->20 layer on a pair of points, j-blocked by 4 (R1's proven structure:
// 4 independent acc chains, SGPR weight bursts, ~59us busy-cycle stream).
template <int JB>
__device__ __forceinline__ void layer20(const float* __restrict__ W,
                                        const float* __restrict__ b,
                                        const v2f* __restrict__ h,
                                        v2f* __restrict__ hn) {
    static_assert(HID % JB == 0, "JB must divide HID");
    #pragma unroll
    for (int jb = 0; jb < HID; jb += JB) {
        v2f acc[JB];
        #pragma unroll
        for (int j = 0; j < JB; ++j) {
            float bj = b[jb + j];
            acc[j] = (v2f){bj, bj};
        }
        #pragma unroll
        for (int i = 0; i < HID; ++i) {
            v2f hi = h[i];
            #pragma unroll
            for (int j = 0; j < JB; ++j) {
                float w = W[(jb + j) * HID + i];
                acc[j] = __builtin_elementwise_fma(hi, (v2f){w, w}, acc[j]);
            }
        }
        #pragma unroll
        for (int j = 0; j < JB; ++j)
            hn[jb + j] = silu2(acc[j]);
    }
}

// R13 change vs R9 (80.3us best): block 256 -> 128 (grid 2048 -> 4096 WGs).
// Evidence: duty/occupancy tracks WG COUNT across all clean runs (2048 WGs
// -> 40% occ / 73% busy; 4096 WGs (R8) -> 69% occ / 89% busy; 1365 -> 37%).
// Per-WG latency ~25-30us vs 80-110us kernel => CP holds only ~3 WGs/CU in
// flight at block=256; more, smaller WGs pack more wave-slots per CU and
// decorrelate the per-layer s_load convoys. Same lean 2-pt stream, same
// 128-VGPR budget ((128,4) min-waves declaration unchanged).
// Tripwires: VGPR ~44, WRITE_SIZE ~4MB.
__global__ __launch_bounds__(128, 4) void SpringEquationNN_70102456205450_kernel(
    const float* __restrict__ t,
    const float* __restrict__ W0, const float* __restrict__ b0,
    const float* __restrict__ W1, const float* __restrict__ b1,
    const float* __restrict__ W2, const float* __restrict__ b2,
    const float* __restrict__ W3, const float* __restrict__ b3,
    const float* __restrict__ W4, const float* __restrict__ b4,
    const float* __restrict__ W5, const float* __restrict__ b5,
    const float* __restrict__ W6, const float* __restrict__ b6,
    const float* __restrict__ W7, const float* __restrict__ b7,
    float* __restrict__ out, int n)
{
    int idx = blockIdx.x * blockDim.x + threadIdx.x;   // pair index
    int p0 = 2 * idx;
    if (p0 >= n) return;

    // Coalesced 8B load of two consecutive points (N is even: 1048576).
    v2f x = *(const v2f*)(t + p0);

    v2f h[HID], hn[HID];

    // Layer 0: 1 -> 20 on both points
    #pragma unroll
    for (int j = 0; j < HID; ++j) {
        float w = W0[j], bb = b0[j];
        v2f a = __builtin_elementwise_fma(x, (v2f){w, w}, (v2f){bb, bb});
        h[j] = silu2(a);
    }

    // Layers 1..6 as 3 iterations x (2 layers). MUST NOT unroll (code size:
    // unrolled 2-pt is ~46KB > 32KB I$, pinned duty at 64-74% in R1-R7;
    // this loop form fits I$ and is the measured best, R9).
    #pragma unroll 1
    for (int it = 0; it < 3; ++it) {
        const float *Wa, *ba_, *Wb, *bb_;
        if (it == 0)      { Wa = W1; ba_ = b1; Wb = W2; bb_ = b2; }
        else if (it == 1) { Wa = W3; ba_ = b3; Wb = W4; bb_ = b4; }
        else              { Wa = W5; ba_ = b5; Wb = W6; bb_ = b6; }
        layer20<4>(Wa, ba_, h, hn);
        layer20<4>(Wb, bb_, hn, h);
    }

    // Layer 7: 20 -> 1 (no activation). Serial ascending-i chain preserves
    // the exact reference summation order.
    float b7v = b7[0];
    v2f acc = {b7v, b7v};
    #pragma unroll
    for (int i = 0; i < HID; ++i) {
        float w = W7[i];
        acc = __builtin_elementwise_fma(h[i], (v2f){w, w}, acc);
    }

    // Coalesced 8B store.
    *(v2f*)(out + p0) = acc;
}

extern "C" void kernel_launch(void* const* d_in, const int* in_sizes, int n_in,
                              void* d_out, int out_size, void* d_ws, size_t ws_size,
                              hipStream_t stream) {
    const float* t  = (const float*)d_in[0];
    const float* W0 = (const float*)d_in[1];
    const float* b0 = (const float*)d_in[2];
    const float* W1 = (const float*)d_in[3];
    const float* b1 = (const float*)d_in[4];
    const float* W2 = (const float*)d_in[5];
    const float* b2 = (const float*)d_in[6];
    const float* W3 = (const float*)d_in[7];
    const float* b3 = (const float*)d_in[8];
    const float* W4 = (const float*)d_in[9];
    const float* b4 = (const float*)d_in[10];
    const float* W5 = (const float*)d_in[11];
    const float* b5 = (const float*)d_in[12];
    const float* W6 = (const float*)d_in[13];
    const float* b6 = (const float*)d_in[14];
    const float* W7 = (const float*)d_in[15];
    const float* b7 = (const float*)d_in[16];
    float* out = (float*)d_out;

    int n = in_sizes[0];             // N points
    int pairs = (n + 1) / 2;         // threads (N=1048576 -> 524288)
    int block = 128;                 // 4096 WGs: R8's WG count, R9's stream
    int grid = (pairs + block - 1) / block;
    SpringEquationNN_70102456205450_kernel<<<grid, block, 0, stream>>>(
        t, W0, b0, W1, b1, W2, b2, W3, b3, W4, b4, W5, b5, W6, b6, W7, b7,
        out, n);
}